// Round 10
// baseline (484.983 us; speedup 1.0000x reference)
//
#include <hip/hip_runtime.h>
#include <hip/hip_cooperative_groups.h>
#include <hip/hip_bf16.h>
#include <math.h>

typedef __bf16 bf16_t;
typedef __attribute__((ext_vector_type(8))) __bf16 bf16x8;
typedef __attribute__((ext_vector_type(4))) float floatx4;

#define SCALE 0.17677669529663689f
#define MFMA __builtin_amdgcn_mfma_f32_16x16x32_bf16

// ---------------------------------------------------------------------------
// SINGLE COOPERATIVE MEGAKERNEL.
// Phase P (all 256 blocks): prep — cb2 bias table, qkv fp32->bf16, proj·lin
// fold — then __threadfence + grid.sync().  (Launch-overhead ladder r0-r9:
// ~35-40 us per launch; 2 launches -> 1 saves ~40-50 us.)
// Phase W (grid-stride, 4 iters/block): the r9 two-window body, unchanged:
//   768 thr = 12 waves = 2 windows x 6 head-waves; spill-free (X re-read
//   from LDS per ks); XL[49][200] + 6 R regions per window; barriers
//   (1) X staged (2) PV done (3) ctx staged (4) loop-end XL/R reuse guard.
// LDS 2 x 40,520 bf16 = 162,080 B.  Empirical: 1 WG/CU -> 256 blocks are
// exactly co-resident (cooperative requirement satisfied).
// ---------------------------------------------------------------------------
__global__ __launch_bounds__(768, 3)
void mega(const float* __restrict__ inp, const float* __restrict__ g,
          const float* __restrict__ bta, const float* __restrict__ qkv_w,
          const float* __restrict__ qkv_b, const float* __restrict__ table,
          const int* __restrict__ rpi, const float* __restrict__ mask,
          const float* __restrict__ proj_w, const float* __restrict__ proj_b,
          const float* __restrict__ lin_w, const float* __restrict__ lin_b,
          bf16_t* __restrict__ cb2, bf16_t* __restrict__ wcvt,
          bf16_t* __restrict__ wfo, float* __restrict__ bfb,
          float* __restrict__ out)
{
    __shared__ __align__(16) bf16_t lds[81040];      // 2 x 40,520 bf16
    const int tid = threadIdx.x;
    const int blk = blockIdx.x;
    const int nthr = gridDim.x * 768;
    const int gtid = blk * 768 + tid;

    // ================= Phase P: prep (grid-strided) =================
    for (int i = gtid; i < 1572864; i += nthr) {     // cb2, C-frag ordered
        int idx = i & 15, lane = (i >> 4) & 63, mt = (i >> 10) & 3, whh_ = i >> 12;
        int win = whh_ / 6, hh_ = whh_ - win * 6;
        int nt = idx >> 2, r = idx & 3;
        int m = mt * 16 + ((lane >> 4)) * 4 + r;
        int j = nt * 16 + (lane & 15);
        float v;
        if (j >= 49)      v = -1e30f;
        else if (m >= 49) v = 0.0f;
        else              v = table[rpi[m * 49 + j] * 6 + hh_] + mask[win * 2401 + m * 49 + j];
        cb2[i] = (bf16_t)v;
    }
    for (int i = gtid; i < 110592; i += nthr)        // qkv fp32 -> bf16
        wcvt[i] = (bf16_t)qkv_w[i];
    for (int idx = gtid; idx < 36864; idx += nthr) { // Wf = lin_w @ proj_w
        int o = idx / 192, i = idx - o * 192;
        float acc = 0.f;
        for (int c = 0; c < 192; ++c)
            acc += lin_w[o * 192 + c] * proj_w[c * 192 + i];
        wfo[o * 192 + i] = (bf16_t)acc;
    }
    for (int o = gtid; o < 192; o += nthr) {         // bf = lin_b + lin_w@proj_b
        float bb = lin_b[o];
        for (int c = 0; c < 192; ++c) bb += lin_w[o * 192 + c] * proj_b[c];
        bfb[o] = bb;
    }
    __threadfence();
    cooperative_groups::this_grid().sync();

    // ================= Phase W: window pairs =================
    const int wv = tid >> 6;                          // 0..11
    const int wwin = wv >= 6 ? 1 : 0;                 // window slot in block
    const int h = wv - wwin * 6;                      // head 0..5
    const int lane = tid & 63;
    const int quad = lane >> 4, lr = lane & 15;
    bf16_t* base = lds + wwin * 40520;
    bf16_t* XL = base;                                // [49][200]
    bf16_t* R  = base + 9800 + h * 5120;              // per-head region

    // predicated X-fragment load: rows >= 49 read as zero
    auto ldx = [&](int mt, int ks) -> bf16x8 {
        bf16x8 z = {};
        int row = mt * 16 + lr;
        if (row < 49) z = *(const bf16x8*)&XL[row * 200 + ks * 32 + quad * 8];
        return z;
    };

    for (int p = blk; p < 1024; p += gridDim.x) {
        const int w = p * 2 + wwin;                   // window id 0..2047
        const int wh = (w & 63) * 6 + h;
        const int b = w >> 6, widx = w & 63;
        const int whh = widx >> 3, www = widx & 7;

        // ---- Phase 0: LayerNorm + gather (shift/partition) into XL ----
        {
            float g0 = g[lane], g1 = g[lane + 64], g2 = g[lane + 128];
            float b0 = bta[lane], b1 = bta[lane + 64], b2 = bta[lane + 128];
            for (int t = h; t < 49; t += 6) {
                int ii = t / 7, jj = t - ii * 7;
                int hh2 = whh * 7 + ii + 3; if (hh2 >= 56) hh2 -= 56;
                int ww2 = www * 7 + jj + 3; if (ww2 >= 56) ww2 -= 56;
                const float* row = inp + ((size_t)(b * 3136 + hh2 * 56 + ww2)) * 192;
                float v0 = row[lane], v1 = row[lane + 64], v2 = row[lane + 128];
                float s = v0 + v1 + v2;
                float sq = v0 * v0 + v1 * v1 + v2 * v2;
#pragma unroll
                for (int off = 32; off > 0; off >>= 1) {
                    s  += __shfl_down(s, off);
                    sq += __shfl_down(sq, off);
                }
                s = __shfl(s, 0); sq = __shfl(sq, 0);
                float mu  = s * (1.0f / 192.0f);
                float var = sq * (1.0f / 192.0f) - mu * mu;
                float inv = rsqrtf(var + 1e-5f);
                XL[t * 200 + lane]       = (bf16_t)((v0 - mu) * inv * g0 + b0);
                XL[t * 200 + lane + 64]  = (bf16_t)((v1 - mu) * inv * g1 + b1);
                XL[t * 200 + lane + 128] = (bf16_t)((v2 - mu) * inv * g2 + b2);
            }
        }
        __syncthreads();   // (1) X staged

        // ---- Phase A1: q,k = X @ Wq,Wk  (64 tok x 64 cols); X from LDS ----
        floatx4 acc[4][4];
#pragma unroll
        for (int mt = 0; mt < 4; ++mt)
#pragma unroll
            for (int nt = 0; nt < 4; ++nt) acc[mt][nt] = floatx4{0.f,0.f,0.f,0.f};

#pragma unroll
        for (int ks = 0; ks < 6; ++ks) {
            bf16x8 wf0 = *(const bf16x8*)(wcvt + (size_t)(h * 32 + lr) * 192 + ks * 32 + quad * 8);
            bf16x8 wf1 = *(const bf16x8*)(wcvt + (size_t)(h * 32 + 16 + lr) * 192 + ks * 32 + quad * 8);
            bf16x8 wf2 = *(const bf16x8*)(wcvt + (size_t)(192 + h * 32 + lr) * 192 + ks * 32 + quad * 8);
            bf16x8 wf3 = *(const bf16x8*)(wcvt + (size_t)(192 + h * 32 + 16 + lr) * 192 + ks * 32 + quad * 8);
#pragma unroll
            for (int mt = 0; mt < 4; ++mt) {
                bf16x8 xk = ldx(mt, ks);
                acc[mt][0] = MFMA(xk, wf0, acc[mt][0], 0, 0, 0);
                acc[mt][1] = MFMA(xk, wf1, acc[mt][1], 0, 0, 0);
                acc[mt][2] = MFMA(xk, wf2, acc[mt][2], 0, 0, 0);
                acc[mt][3] = MFMA(xk, wf3, acc[mt][3], 0, 0, 0);
            }
        }
        {
            float bq0 = qkv_b[h * 32 + lr],       bq1 = qkv_b[h * 32 + 16 + lr];
            float bk0 = qkv_b[192 + h * 32 + lr], bk1 = qkv_b[192 + h * 32 + 16 + lr];
#pragma unroll
            for (int mt = 0; mt < 4; ++mt)
#pragma unroll
                for (int r = 0; r < 4; ++r) {
                    int tok = mt * 16 + quad * 4 + r;
                    R[tok * 40 + lr]             = (bf16_t)((acc[mt][0][r] + bq0) * SCALE);
                    R[tok * 40 + 16 + lr]        = (bf16_t)((acc[mt][1][r] + bq1) * SCALE);
                    R[2560 + tok * 40 + lr]      = (bf16_t)(acc[mt][2][r] + bk0);
                    R[2560 + tok * 40 + 16 + lr] = (bf16_t)(acc[mt][3][r] + bk1);
                }
        }

        // ---- QK^T (64x64, K=32) ----
        bf16x8 qf[4], kf[4];
#pragma unroll
        for (int t = 0; t < 4; ++t) {
            qf[t] = *(const bf16x8*)&R[(t * 16 + lr) * 40 + quad * 8];
            kf[t] = *(const bf16x8*)&R[2560 + (t * 16 + lr) * 40 + quad * 8];
        }
        floatx4 s[4][4];
#pragma unroll
        for (int mt = 0; mt < 4; ++mt)
#pragma unroll
            for (int nt = 0; nt < 4; ++nt) s[mt][nt] = floatx4{0.f,0.f,0.f,0.f};
#pragma unroll
        for (int mt = 0; mt < 4; ++mt)
#pragma unroll
            for (int nt = 0; nt < 4; ++nt)
                s[mt][nt] = MFMA(qf[mt], kf[nt], s[mt][nt], 0, 0, 0);

        // bias + mask (C-frag ordered)
        const bf16_t* cb = cb2 + (((size_t)wh * 4) * 64 + lane) * 16;
#pragma unroll
        for (int mt = 0; mt < 4; ++mt) {
            bf16x8 c0 = *(const bf16x8*)(cb + (size_t)mt * 1024);
            bf16x8 c1 = *(const bf16x8*)(cb + (size_t)mt * 1024 + 8);
#pragma unroll
            for (int r = 0; r < 4; ++r) {
                s[mt][0][r] += (float)c0[r];
                s[mt][1][r] += (float)c0[4 + r];
                s[mt][2][r] += (float)c1[r];
                s[mt][3][r] += (float)c1[4 + r];
            }
        }

        // in-register row softmax (row spread over 16 lr lanes x 4 nt regs)
#pragma unroll
        for (int mt = 0; mt < 4; ++mt) {
#pragma unroll
            for (int r = 0; r < 4; ++r) {
                float mx = fmaxf(fmaxf(s[mt][0][r], s[mt][1][r]),
                                 fmaxf(s[mt][2][r], s[mt][3][r]));
#pragma unroll
                for (int off = 1; off < 16; off <<= 1)
                    mx = fmaxf(mx, __shfl_xor(mx, off));
                float sum = 0.f;
#pragma unroll
                for (int nt = 0; nt < 4; ++nt) {
                    float e = __expf(s[mt][nt][r] - mx);
                    s[mt][nt][r] = e; sum += e;
                }
#pragma unroll
                for (int off = 1; off < 16; off <<= 1)
                    sum += __shfl_xor(sum, off);
                float inv = 1.0f / sum;
#pragma unroll
                for (int nt = 0; nt < 4; ++nt) s[mt][nt][r] *= inv;
            }
        }

        // ---- P -> LDS (overwrites q/k; wave-private), pull A-frags of P ----
#pragma unroll
        for (int mt = 0; mt < 4; ++mt)
#pragma unroll
            for (int nt = 0; nt < 4; ++nt)
#pragma unroll
                for (int r = 0; r < 4; ++r)
                    R[(mt * 16 + quad * 4 + r) * 72 + nt * 16 + lr] = (bf16_t)s[mt][nt][r];
        bf16x8 pf[4][2];
#pragma unroll
        for (int mt = 0; mt < 4; ++mt)
#pragma unroll
            for (int kt = 0; kt < 2; ++kt)
                pf[mt][kt] = *(const bf16x8*)&R[(mt * 16 + lr) * 72 + kt * 32 + quad * 8];

        // ---- Phase A2: v = X @ Wv (64 tok x 32 d); X re-read from LDS ----
        floatx4 va[4][2];
#pragma unroll
        for (int mt = 0; mt < 4; ++mt) { va[mt][0] = floatx4{0.f,0.f,0.f,0.f}; va[mt][1] = floatx4{0.f,0.f,0.f,0.f}; }
#pragma unroll
        for (int ks = 0; ks < 6; ++ks) {
            bf16x8 wv0 = *(const bf16x8*)(wcvt + (size_t)(384 + h * 32 + lr) * 192 + ks * 32 + quad * 8);
            bf16x8 wv1 = *(const bf16x8*)(wcvt + (size_t)(384 + h * 32 + 16 + lr) * 192 + ks * 32 + quad * 8);
#pragma unroll
            for (int mt = 0; mt < 4; ++mt) {
                bf16x8 xk = ldx(mt, ks);
                va[mt][0] = MFMA(xk, wv0, va[mt][0], 0, 0, 0);
                va[mt][1] = MFMA(xk, wv1, va[mt][1], 0, 0, 0);
            }
        }
        // vT into P region rows 0..31 (P frags already in regs; DS in-order)
        {
            float bv0 = qkv_b[384 + h * 32 + lr], bv1 = qkv_b[384 + h * 32 + 16 + lr];
#pragma unroll
            for (int mt = 0; mt < 4; ++mt)
#pragma unroll
                for (int r = 0; r < 4; ++r) {
                    int tok = mt * 16 + quad * 4 + r;
                    R[lr * 72 + tok]        = (bf16_t)(va[mt][0][r] + bv0);
                    R[(16 + lr) * 72 + tok] = (bf16_t)(va[mt][1][r] + bv1);
                }
        }

        // ---- PV (64 x 32, K=64) ----
        bf16x8 vf[2][2];
#pragma unroll
        for (int nt = 0; nt < 2; ++nt)
#pragma unroll
            for (int kt = 0; kt < 2; ++kt)
                vf[nt][kt] = *(const bf16x8*)&R[(nt * 16 + lr) * 72 + kt * 32 + quad * 8];
        floatx4 c[4][2];
#pragma unroll
        for (int mt = 0; mt < 4; ++mt) { c[mt][0] = floatx4{0.f,0.f,0.f,0.f}; c[mt][1] = floatx4{0.f,0.f,0.f,0.f}; }
#pragma unroll
        for (int mt = 0; mt < 4; ++mt)
#pragma unroll
            for (int nt = 0; nt < 2; ++nt) {
                c[mt][nt] = MFMA(pf[mt][0], vf[nt][0], c[mt][nt], 0, 0, 0);
                c[mt][nt] = MFMA(pf[mt][1], vf[nt][1], c[mt][nt], 0, 0, 0);
            }
        __syncthreads();   // (2) all XL/R reads done; ctx may overwrite XL

        // ---- ctx -> XL [49][200] (rows >= 49 discarded) ----
#pragma unroll
        for (int mt = 0; mt < 4; ++mt)
#pragma unroll
            for (int nt = 0; nt < 2; ++nt)
#pragma unroll
                for (int r = 0; r < 4; ++r) {
                    int tok = mt * 16 + quad * 4 + r;
                    if (tok < 49)
                        XL[tok * 200 + h * 32 + nt * 16 + lr] = (bf16_t)c[mt][nt][r];
                }
        __syncthreads();   // (3) ctx of all heads staged

        // ---- folded lin: out = resid + gelu(ctx @ Wf^T + bf) ----
        floatx4 pr[4][2];
#pragma unroll
        for (int mt = 0; mt < 4; ++mt) { pr[mt][0] = floatx4{0.f,0.f,0.f,0.f}; pr[mt][1] = floatx4{0.f,0.f,0.f,0.f}; }
#pragma unroll
        for (int ks = 0; ks < 6; ++ks) {
            bf16x8 w0 = *(const bf16x8*)(wfo + (size_t)(h * 32 + lr) * 192 + ks * 32 + quad * 8);
            bf16x8 w1 = *(const bf16x8*)(wfo + (size_t)(h * 32 + 16 + lr) * 192 + ks * 32 + quad * 8);
#pragma unroll
            for (int mt = 0; mt < 4; ++mt) {
                bf16x8 af = ldx(mt, ks);   // ctx fragment; rows >= 49 zero
                pr[mt][0] = MFMA(af, w0, pr[mt][0], 0, 0, 0);
                pr[mt][1] = MFMA(af, w1, pr[mt][1], 0, 0, 0);
            }
        }
        // epilogue: bias + gelu + residual, window-reverse + unshift scatter
        {
            float pb0 = bfb[h * 32 + lr], pb1 = bfb[h * 32 + 16 + lr];
#pragma unroll
            for (int mt = 0; mt < 4; ++mt)
#pragma unroll
                for (int r = 0; r < 4; ++r) {
                    int m = mt * 16 + quad * 4 + r;
                    if (m < 49) {
                        int ii = m / 7, jj = m - ii * 7;
                        int hh2 = whh * 7 + ii + 3; if (hh2 >= 56) hh2 -= 56;
                        int ww2 = www * 7 + jj + 3; if (ww2 >= 56) ww2 -= 56;
                        size_t base2 = ((size_t)(b * 3136 + hh2 * 56 + ww2)) * 192 + h * 32;
                        float v0 = pr[mt][0][r] + pb0;
                        float v1 = pr[mt][1][r] + pb1;
                        float gx0 = 0.5f * v0 * (1.0f + erff(v0 * 0.70710678118654752f));
                        float gx1 = 0.5f * v1 * (1.0f + erff(v1 * 0.70710678118654752f));
                        out[base2 + lr]      = inp[base2 + lr]      + gx0;
                        out[base2 + 16 + lr] = inp[base2 + 16 + lr] + gx1;
                    }
                }
        }
        __syncthreads();   // (4) XL/R reuse guard for next iteration
    }
}

// ---------------------------------------------------------------------------
extern "C" void kernel_launch(void* const* d_in, const int* in_sizes, int n_in,
                              void* d_out, int out_size, void* d_ws, size_t ws_size,
                              hipStream_t stream)
{
    const float* inp    = (const float*)d_in[0];
    const float* mask   = (const float*)d_in[1];
    const float* g      = (const float*)d_in[2];
    const float* bta    = (const float*)d_in[3];
    const float* qkv_w  = (const float*)d_in[4];
    const float* qkv_b  = (const float*)d_in[5];
    const float* table  = (const float*)d_in[6];
    const int*   rpi    = (const int*)d_in[7];
    const float* proj_w = (const float*)d_in[8];
    const float* proj_b = (const float*)d_in[9];
    const float* lin_w  = (const float*)d_in[10];
    const float* lin_b  = (const float*)d_in[11];
    float* out = (float*)d_out;

    char* ws = (char*)d_ws;
    bf16_t* wcvt = (bf16_t*)(ws);                 // qkv bf16: 221,184 B
    bf16_t* wfo  = wcvt + 110592;                 // folded Wf: 73,728 B
    float*  bfb  = (float*)(ws + 294912);         // folded bias: 768 B
    bf16_t* cb2  = (bf16_t*)(ws + 300032);        // 3,145,728 B (16B aligned)

    void* args[] = { (void*)&inp, (void*)&g, (void*)&bta, (void*)&qkv_w,
                     (void*)&qkv_b, (void*)&table, (void*)&rpi, (void*)&mask,
                     (void*)&proj_w, (void*)&proj_b, (void*)&lin_w, (void*)&lin_b,
                     (void*)&cb2, (void*)&wcvt, (void*)&wfo, (void*)&bfb,
                     (void*)&out };
    hipLaunchCooperativeKernel((const void*)mega, dim3(256), dim3(768),
                               (void**)args, 0, stream);
}